// Round 1
// baseline (1795.618 us; speedup 1.0000x reference)
//
#include <hip/hip_runtime.h>
#include <cmath>

#define H_ 256
#define W_ 256
#define SEG 4
#define REC_STRIDE 24  // floats per face record

// ---------------- transform: v_pix = [Kx/z, Ky/z, z] ----------------
__global__ void k_transform(const float* __restrict__ verts, const float* __restrict__ Km,
                            const float* __restrict__ Rt, float* __restrict__ vpix,
                            int B, int V) {
  int i = blockIdx.x * blockDim.x + threadIdx.x;
  if (i >= B * V) return;
  int b = i / V;
  float x = verts[(size_t)i * 3 + 0], y = verts[(size_t)i * 3 + 1], z = verts[(size_t)i * 3 + 2];
  const float* R = Rt + (size_t)b * 12;
  float cx = __fadd_rn(__fadd_rn(__fadd_rn(__fmul_rn(R[0], x), __fmul_rn(R[1], y)), __fmul_rn(R[2], z)), R[3]);
  float cy = __fadd_rn(__fadd_rn(__fadd_rn(__fmul_rn(R[4], x), __fmul_rn(R[5], y)), __fmul_rn(R[6], z)), R[7]);
  float cz = __fadd_rn(__fadd_rn(__fadd_rn(__fmul_rn(R[8], x), __fmul_rn(R[9], y)), __fmul_rn(R[10], z)), R[11]);
  const float* Kb = Km + (size_t)b * 9;
  float px = __fadd_rn(__fadd_rn(__fmul_rn(Kb[0], cx), __fmul_rn(Kb[1], cy)), __fmul_rn(Kb[2], cz));
  float py = __fadd_rn(__fadd_rn(__fmul_rn(Kb[3], cx), __fmul_rn(Kb[4], cy)), __fmul_rn(Kb[5], cz));
  vpix[(size_t)i * 3 + 0] = __fdiv_rn(px, cz);
  vpix[(size_t)i * 3 + 1] = __fdiv_rn(py, cz);
  vpix[(size_t)i * 3 + 2] = cz;
}

// ---------------- per-face precompute ----------------
// rec layout (24 floats): ax,ay,bx,by,cx,cy, e0x,e0y,e1x,e1y,e2x,e2y,
//                         za,zb,zc, sprime, ar, minx,maxx,miny,maxy, pad*3
__global__ void k_faceprep(const float* __restrict__ vpix, const int* __restrict__ vi,
                           float* __restrict__ rec, int B, int V, int F) {
  int i = blockIdx.x * blockDim.x + threadIdx.x;
  if (i >= B * F) return;
  int b = i / F, f = i - b * F;
  int i0 = vi[f * 3 + 0], i1 = vi[f * 3 + 1], i2 = vi[f * 3 + 2];
  const float* base = vpix + (size_t)b * V * 3;
  float ax = base[(size_t)i0 * 3], ay = base[(size_t)i0 * 3 + 1], az = base[(size_t)i0 * 3 + 2];
  float bx = base[(size_t)i1 * 3], by = base[(size_t)i1 * 3 + 1], bz = base[(size_t)i1 * 3 + 2];
  float cx = base[(size_t)i2 * 3], cy = base[(size_t)i2 * 3 + 1], cz = base[(size_t)i2 * 3 + 2];
  float e0x = __fsub_rn(cx, bx), e0y = __fsub_rn(cy, by);
  float e1x = __fsub_rn(ax, cx), e1y = __fsub_rn(ay, cy);
  float e2x = __fsub_rn(bx, ax), e2y = __fsub_rn(by, ay);
  // area = (b.x-a.x)*(c.y-a.y) - (b.y-a.y)*(c.x-a.x)
  float area = __fsub_rn(__fmul_rn(e2x, __fsub_rn(cy, ay)), __fmul_rn(e2y, __fsub_rn(cx, ax)));
  float s = (area > 0.f) ? 1.f : ((area < 0.f) ? -1.f : 0.f);
  bool nz = fabsf(area) > 1e-8f;
  bool zv = (az > 0.f) && (bz > 0.f) && (cz > 0.f);
  float sprime = (nz && zv) ? s : __uint_as_float(0x7fc00000u);  // NaN kills all >=0 tests
  float ar = nz ? area : 1.0f;
  float* r = rec + (size_t)i * REC_STRIDE;
  r[0] = ax; r[1] = ay; r[2] = bx; r[3] = by; r[4] = cx; r[5] = cy;
  r[6] = e0x; r[7] = e0y; r[8] = e1x; r[9] = e1y; r[10] = e2x; r[11] = e2y;
  r[12] = az; r[13] = bz; r[14] = cz; r[15] = sprime; r[16] = ar;
  r[17] = fminf(ax, fminf(bx, cx));  // minx
  r[18] = fmaxf(ax, fmaxf(bx, cx));  // maxx
  r[19] = fminf(ay, fminf(by, cy));  // miny
  r[20] = fmaxf(ay, fmaxf(by, cy));  // maxy
  r[21] = 0.f; r[22] = 0.f; r[23] = 0.f;
}

__global__ void k_initkeys(unsigned long long* __restrict__ keys, int n) {
  int i = blockIdx.x * blockDim.x + threadIdx.x;
  if (i < n) keys[i] = 0x7f800000FFFFFFFFull;  // (inf, -1)
}

// ---------------- rasterize: one row per block, SEG face segments ----------------
__global__ __launch_bounds__(256) void k_raster(const float* __restrict__ rec,
                                                unsigned long long* __restrict__ keys,
                                                int B, int F) {
  int x = threadIdx.x;
  int y = blockIdx.x;            // one row per block -> py is wave-uniform
  int b = blockIdx.y;
  int seg = blockIdx.z;
  int f0 = (int)((long long)seg * F / SEG);
  int f1 = (int)((long long)(seg + 1) * F / SEG);
  float px = x + 0.5f, py = y + 0.5f;
  float bestz = INFINITY; int besti = -1;
  const float* rb = rec + (size_t)b * F * REC_STRIDE;
  for (int f = f0; f < f1; ++f) {
    const float* r = rb + (size_t)f * REC_STRIDE;
    float miny = r[19], maxy = r[20], minx = r[17], maxx = r[18];
    // block-uniform row/viewport rejection (conservative: inside => within bbox)
    if (py < miny || py > maxy || maxx < 0.5f || minx > (float)W_ - 0.5f) continue;
    float ax = r[0], ay = r[1], bx = r[2], by = r[3], cx = r[4], cy = r[5];
    float e0x = r[6], e0y = r[7], e1x = r[8], e1y = r[9], e2x = r[10], e2y = r[11];
    float za = r[12], zb = r[13], zc = r[14], sp = r[15], ar = r[16];
    float w0 = __fsub_rn(__fmul_rn(e0x, __fsub_rn(py, by)), __fmul_rn(e0y, __fsub_rn(px, bx)));
    float w1 = __fsub_rn(__fmul_rn(e1x, __fsub_rn(py, cy)), __fmul_rn(e1y, __fsub_rn(px, cx)));
    float w2 = __fsub_rn(__fmul_rn(e2x, __fsub_rn(py, ay)), __fmul_rn(e2y, __fsub_rn(px, ax)));
    bool inside = (__fmul_rn(w0, sp) >= 0.f) && (__fmul_rn(w1, sp) >= 0.f) && (__fmul_rn(w2, sp) >= 0.f);
    if (inside) {
      float t0 = __fdiv_rn(__fdiv_rn(w0, ar), za);
      float t1 = __fdiv_rn(__fdiv_rn(w1, ar), zb);
      float t2 = __fdiv_rn(__fdiv_rn(w2, ar), zc);
      float invz = __fadd_rn(__fadd_rn(t0, t1), t2);
      if (invz > 0.f) {
        float z = __fdiv_rn(1.0f, fmaxf(invz, 1e-12f));
        if (z < bestz) { bestz = z; besti = f; }
      }
    }
  }
  if (besti >= 0) {
    unsigned long long key = ((unsigned long long)__float_as_uint(bestz) << 32) | (unsigned)besti;
    atomicMin(&keys[(size_t)b * (H_ * W_) + y * W_ + x], key);
  }
}

__global__ void k_resolve(const unsigned long long* __restrict__ keys, float* __restrict__ idxout, int n) {
  int i = blockIdx.x * blockDim.x + threadIdx.x;
  if (i >= n) return;
  unsigned long long k = keys[i];
  unsigned zb = (unsigned)(k >> 32);
  idxout[i] = (zb >= 0x7f800000u) ? -1.0f : (float)(int)(unsigned)(k & 0xffffffffu);
}

// ---------------- fallback rasterizer (no workspace needed) ----------------
__global__ void k_raster_direct(const float* __restrict__ vpix, const int* __restrict__ vi,
                                float* __restrict__ idxout, int B, int V, int F) {
  int p = blockIdx.x * blockDim.x + threadIdx.x;
  if (p >= B * H_ * W_) return;
  int b = p / (H_ * W_); int pid = p - b * (H_ * W_);
  float px = (pid & (W_ - 1)) + 0.5f, py = (pid >> 8) + 0.5f;
  const float* base = vpix + (size_t)b * V * 3;
  float bestz = INFINITY; int besti = -1;
  for (int f = 0; f < F; ++f) {
    int i0 = vi[f * 3], i1 = vi[f * 3 + 1], i2 = vi[f * 3 + 2];
    float ax = base[(size_t)i0 * 3], ay = base[(size_t)i0 * 3 + 1], za = base[(size_t)i0 * 3 + 2];
    float bx = base[(size_t)i1 * 3], by = base[(size_t)i1 * 3 + 1], zb = base[(size_t)i1 * 3 + 2];
    float cx = base[(size_t)i2 * 3], cy = base[(size_t)i2 * 3 + 1], zc = base[(size_t)i2 * 3 + 2];
    float e0x = __fsub_rn(cx, bx), e0y = __fsub_rn(cy, by);
    float e1x = __fsub_rn(ax, cx), e1y = __fsub_rn(ay, cy);
    float e2x = __fsub_rn(bx, ax), e2y = __fsub_rn(by, ay);
    float area = __fsub_rn(__fmul_rn(e2x, __fsub_rn(cy, ay)), __fmul_rn(e2y, __fsub_rn(cx, ax)));
    float s = (area > 0.f) ? 1.f : ((area < 0.f) ? -1.f : 0.f);
    bool nz = fabsf(area) > 1e-8f;
    bool zv = (za > 0.f) && (zb > 0.f) && (zc > 0.f);
    float sp = (nz && zv) ? s : __uint_as_float(0x7fc00000u);
    float ar = nz ? area : 1.0f;
    float w0 = __fsub_rn(__fmul_rn(e0x, __fsub_rn(py, by)), __fmul_rn(e0y, __fsub_rn(px, bx)));
    float w1 = __fsub_rn(__fmul_rn(e1x, __fsub_rn(py, cy)), __fmul_rn(e1y, __fsub_rn(px, cx)));
    float w2 = __fsub_rn(__fmul_rn(e2x, __fsub_rn(py, ay)), __fmul_rn(e2y, __fsub_rn(px, ax)));
    bool inside = (__fmul_rn(w0, sp) >= 0.f) && (__fmul_rn(w1, sp) >= 0.f) && (__fmul_rn(w2, sp) >= 0.f);
    if (inside) {
      float invz = __fadd_rn(__fadd_rn(__fdiv_rn(__fdiv_rn(w0, ar), za),
                                       __fdiv_rn(__fdiv_rn(w1, ar), zb)),
                             __fdiv_rn(__fdiv_rn(w2, ar), zc));
      if (invz > 0.f) {
        float z = __fdiv_rn(1.0f, fmaxf(invz, 1e-12f));
        if (z < bestz) { bestz = z; besti = f; }
      }
    }
  }
  idxout[p] = (float)besti;
}

// ---------------- render + interpolate + grid_sample, fused ----------------
__global__ __launch_bounds__(256) void k_render(const float* __restrict__ vpix, const int* __restrict__ vi,
                                                const int* __restrict__ vti, const float* __restrict__ vt,
                                                const float* __restrict__ tex, const float* __restrict__ idxin,
                                                float* __restrict__ o_img, float* __restrict__ o_depth,
                                                float* __restrict__ o_vt, float* __restrict__ o_bary,
                                                float* __restrict__ o_mask,
                                                int B, int V, int F, int TH, int TW) {
  int p = blockIdx.x * blockDim.x + threadIdx.x;
  if (p >= B * H_ * W_) return;
  int HW = H_ * W_;
  int b = p / HW; int pid = p - b * HW;
  int y = pid >> 8, x = pid & (W_ - 1);
  int idx = (int)idxin[p];
  size_t pix2 = (size_t)b * 2 * HW + pid;  // plane-0 index for (B,2,H,W)
  size_t pix3 = (size_t)b * 3 * HW + pid;  // plane-0 index for (B,3,H,W)
  if (idx < 0) {
    o_depth[p] = 0.f; o_mask[p] = 0.f;
    o_vt[pix2] = 0.f; o_vt[pix2 + HW] = 0.f;
    o_bary[pix3] = 0.f; o_bary[pix3 + HW] = 0.f; o_bary[pix3 + 2 * HW] = 0.f;
    o_img[pix3] = 0.f; o_img[pix3 + HW] = 0.f; o_img[pix3 + 2 * HW] = 0.f;
    return;
  }
  const float* base = vpix + (size_t)b * V * 3;
  int i0 = vi[idx * 3], i1 = vi[idx * 3 + 1], i2 = vi[idx * 3 + 2];
  float ax = base[(size_t)i0 * 3], ay = base[(size_t)i0 * 3 + 1], az = base[(size_t)i0 * 3 + 2];
  float bx = base[(size_t)i1 * 3], by = base[(size_t)i1 * 3 + 1], bz = base[(size_t)i1 * 3 + 2];
  float cx = base[(size_t)i2 * 3], cy = base[(size_t)i2 * 3 + 1], cz = base[(size_t)i2 * 3 + 2];
  float ptx = x + 0.5f, pty = y + 0.5f;
  float w0 = __fsub_rn(__fmul_rn(__fsub_rn(cx, bx), __fsub_rn(pty, by)),
                       __fmul_rn(__fsub_rn(cy, by), __fsub_rn(ptx, bx)));
  float w1 = __fsub_rn(__fmul_rn(__fsub_rn(ax, cx), __fsub_rn(pty, cy)),
                       __fmul_rn(__fsub_rn(ay, cy), __fsub_rn(ptx, cx)));
  float w2 = __fsub_rn(__fmul_rn(__fsub_rn(bx, ax), __fsub_rn(pty, ay)),
                       __fmul_rn(__fsub_rn(by, ay), __fsub_rn(ptx, ax)));
  float area = __fadd_rn(__fadd_rn(w0, w1), w2);
  float ar = (fabsf(area) > 1e-8f) ? area : 1.0f;
  float f0 = __fdiv_rn(__fdiv_rn(w0, ar), fmaxf(az, 1e-8f));
  float f1 = __fdiv_rn(__fdiv_rn(w1, ar), fmaxf(bz, 1e-8f));
  float f2 = __fdiv_rn(__fdiv_rn(w2, ar), fmaxf(cz, 1e-8f));
  float invz = __fadd_rn(__fadd_rn(f0, f1), f2);
  float invz_s = (fabsf(invz) > 1e-12f) ? invz : 1.0f;
  float depth = __fdiv_rn(1.0f, invz_s);
  float bary0 = __fdiv_rn(f0, invz_s);
  float bary1 = __fdiv_rn(f1, invz_s);
  float bary2 = __fdiv_rn(f2, invz_s);
  o_depth[p] = depth; o_mask[p] = 1.0f;
  o_bary[pix3] = bary0; o_bary[pix3 + HW] = bary1; o_bary[pix3 + 2 * HW] = bary2;
  // interpolate vt (vt*2-1) with bary
  int t0 = vti[idx * 3], t1 = vti[idx * 3 + 1], t2 = vti[idx * 3 + 2];
  float u0x = __fsub_rn(__fmul_rn(vt[(size_t)t0 * 2], 2.f), 1.f);
  float u0y = __fsub_rn(__fmul_rn(vt[(size_t)t0 * 2 + 1], 2.f), 1.f);
  float u1x = __fsub_rn(__fmul_rn(vt[(size_t)t1 * 2], 2.f), 1.f);
  float u1y = __fsub_rn(__fmul_rn(vt[(size_t)t1 * 2 + 1], 2.f), 1.f);
  float u2x = __fsub_rn(__fmul_rn(vt[(size_t)t2 * 2], 2.f), 1.f);
  float u2y = __fsub_rn(__fmul_rn(vt[(size_t)t2 * 2 + 1], 2.f), 1.f);
  float gx = __fadd_rn(__fadd_rn(__fmul_rn(u0x, bary0), __fmul_rn(u1x, bary1)), __fmul_rn(u2x, bary2));
  float gy = __fadd_rn(__fadd_rn(__fmul_rn(u0y, bary0), __fmul_rn(u1y, bary1)), __fmul_rn(u2y, bary2));
  o_vt[pix2] = gx; o_vt[pix2 + HW] = gy;
  // grid_sample bilinear, zero padding
  float sx = __fsub_rn(__fdiv_rn(__fmul_rn(__fadd_rn(gx, 1.0f), (float)TW), 2.0f), 0.5f);
  float sy = __fsub_rn(__fdiv_rn(__fmul_rn(__fadd_rn(gy, 1.0f), (float)TH), 2.0f), 0.5f);
  float x0f = floorf(sx), y0f = floorf(sy);
  float wx = __fsub_rn(sx, x0f), wy = __fsub_rn(sy, y0f);
  float omx = __fsub_rn(1.0f, wx), omy = __fsub_rn(1.0f, wy);
  int x0 = (int)x0f, y0 = (int)y0f;
  int x1 = x0 + 1, y1 = y0 + 1;
  bool v00 = (x0 >= 0) && (x0 < TW) && (y0 >= 0) && (y0 < TH);
  bool v10 = (x1 >= 0) && (x1 < TW) && (y0 >= 0) && (y0 < TH);
  bool v01 = (x0 >= 0) && (x0 < TW) && (y1 >= 0) && (y1 < TH);
  bool v11 = (x1 >= 0) && (x1 < TW) && (y1 >= 0) && (y1 < TH);
  int x0c = min(max(x0, 0), TW - 1), x1c = min(max(x1, 0), TW - 1);
  int y0c = min(max(y0, 0), TH - 1), y1c = min(max(y1, 0), TH - 1);
  const float* tb = tex + (size_t)b * 3 * TH * TW;
  #pragma unroll
  for (int ch = 0; ch < 3; ++ch) {
    const float* tc = tb + (size_t)ch * TH * TW;
    float g00 = v00 ? tc[(size_t)y0c * TW + x0c] : 0.f;
    float g10 = v10 ? tc[(size_t)y0c * TW + x1c] : 0.f;
    float g01 = v01 ? tc[(size_t)y1c * TW + x0c] : 0.f;
    float g11 = v11 ? tc[(size_t)y1c * TW + x1c] : 0.f;
    float r = __fmul_rn(__fmul_rn(g00, omx), omy);
    r = __fadd_rn(r, __fmul_rn(__fmul_rn(g10, wx), omy));
    r = __fadd_rn(r, __fmul_rn(__fmul_rn(g01, omx), wy));
    r = __fadd_rn(r, __fmul_rn(__fmul_rn(g11, wx), wy));
    o_img[pix3 + (size_t)ch * HW] = r;  // mask == 1 here
  }
}

extern "C" void kernel_launch(void* const* d_in, const int* in_sizes, int n_in,
                              void* d_out, int out_size, void* d_ws, size_t ws_size,
                              hipStream_t stream) {
  const float* verts = (const float*)d_in[0];
  const float* tex   = (const float*)d_in[1];
  const float* Km    = (const float*)d_in[2];
  const float* Rt    = (const float*)d_in[3];
  const float* vt    = (const float*)d_in[4];
  const int*   vi    = (const int*)d_in[5];
  const int*   vti   = (const int*)d_in[6];

  int B = in_sizes[2] / 9;
  int V = in_sizes[0] / (3 * B);
  int F = in_sizes[5] / 3;
  long texhw = (long)in_sizes[1] / (B * 3);
  int TH = (int)(sqrt((double)texhw) + 0.5);
  int TW = TH;
  const int HW = H_ * W_;

  float* out = (float*)d_out;
  float* o_img   = out;
  float* o_depth = o_img + (size_t)B * 3 * HW;
  float* o_vpix  = o_depth + (size_t)B * HW;
  float* o_vt    = o_vpix + (size_t)B * V * 3;
  float* o_idx   = o_vt + (size_t)B * 2 * HW;
  float* o_bary  = o_idx + (size_t)B * HW;
  float* o_mask  = o_bary + (size_t)B * 3 * HW;

  k_transform<<<(B * V + 255) / 256, 256, 0, stream>>>(verts, Km, Rt, o_vpix, B, V);

  size_t keysBytes = (size_t)B * HW * 8;
  size_t recBytes = (size_t)B * F * REC_STRIDE * 4;
  if (ws_size >= keysBytes + recBytes) {
    unsigned long long* keys = (unsigned long long*)d_ws;
    float* rec = (float*)((char*)d_ws + keysBytes);
    k_faceprep<<<(B * F + 255) / 256, 256, 0, stream>>>(o_vpix, vi, rec, B, V, F);
    k_initkeys<<<(B * HW + 255) / 256, 256, 0, stream>>>(keys, B * HW);
    dim3 rg(H_, B, SEG);
    k_raster<<<rg, 256, 0, stream>>>(rec, keys, B, F);
    k_resolve<<<(B * HW + 255) / 256, 256, 0, stream>>>(keys, o_idx, B * HW);
  } else {
    k_raster_direct<<<(B * HW + 255) / 256, 256, 0, stream>>>(o_vpix, vi, o_idx, B, V, F);
  }

  k_render<<<(B * HW + 255) / 256, 256, 0, stream>>>(o_vpix, vi, vti, vt, tex, o_idx,
                                                     o_img, o_depth, o_vt, o_bary, o_mask,
                                                     B, V, F, TH, TW);
}

// Round 2
// 515.070 us; speedup vs baseline: 3.4862x; 3.4862x over previous
//
#include <hip/hip_runtime.h>
#include <cmath>

#define H_ 256
#define W_ 256
#define SEG 4
#define NB 256          // sort buckets
#define ILV 8           // face-interleave factor for sorted raster
#define REC_STRIDE 24   // floats per face record

__device__ inline unsigned fkey(float f) {
  unsigned u = __float_as_uint(f);
  return (u & 0x80000000u) ? ~u : (u | 0x80000000u);
}
__device__ inline float unfkey(unsigned k) {
  return (k & 0x80000000u) ? __uint_as_float(k & 0x7fffffffu) : __uint_as_float(~k);
}

// ---------------- transform: v_pix = [Kx/z, Ky/z, z] ----------------
__global__ void k_transform(const float* __restrict__ verts, const float* __restrict__ Km,
                            const float* __restrict__ Rt, float* __restrict__ vpix,
                            int B, int V) {
  int i = blockIdx.x * blockDim.x + threadIdx.x;
  if (i >= B * V) return;
  int b = i / V;
  float x = verts[(size_t)i * 3 + 0], y = verts[(size_t)i * 3 + 1], z = verts[(size_t)i * 3 + 2];
  const float* R = Rt + (size_t)b * 12;
  float cx = __fadd_rn(__fadd_rn(__fadd_rn(__fmul_rn(R[0], x), __fmul_rn(R[1], y)), __fmul_rn(R[2], z)), R[3]);
  float cy = __fadd_rn(__fadd_rn(__fadd_rn(__fmul_rn(R[4], x), __fmul_rn(R[5], y)), __fmul_rn(R[6], z)), R[7]);
  float cz = __fadd_rn(__fadd_rn(__fadd_rn(__fmul_rn(R[8], x), __fmul_rn(R[9], y)), __fmul_rn(R[10], z)), R[11]);
  const float* Kb = Km + (size_t)b * 9;
  float px = __fadd_rn(__fadd_rn(__fmul_rn(Kb[0], cx), __fmul_rn(Kb[1], cy)), __fmul_rn(Kb[2], cz));
  float py = __fadd_rn(__fadd_rn(__fmul_rn(Kb[3], cx), __fmul_rn(Kb[4], cy)), __fmul_rn(Kb[5], cz));
  vpix[(size_t)i * 3 + 0] = __fdiv_rn(px, cz);
  vpix[(size_t)i * 3 + 1] = __fdiv_rn(py, cz);
  vpix[(size_t)i * 3 + 2] = cz;
}

// ---------------- init workspace ----------------
__global__ void k_init(unsigned long long* __restrict__ keys, int nkeys,
                       int* __restrict__ hist, int* __restrict__ cursor, int nbkt,
                       unsigned* __restrict__ minmax) {
  int i = blockIdx.x * blockDim.x + threadIdx.x;
  if (i < nkeys) keys[i] = 0x7f800000FFFFFFFFull;  // (inf, -1)
  if (i < nbkt) { hist[i] = 0; cursor[i] = 0; }
  if (i == 0 && minmax) { minmax[0] = 0xFFFFFFFFu; minmax[1] = 0u; }
}

// ---------------- per-face precompute ----------------
// rec: ax,ay,bx,by,cx,cy, e0x,e0y,e1x,e1y,e2x,e2y, za,zb,zc, sprime, ar,
//      minx,maxx,miny,maxy, zmin, pad*2
__global__ void k_faceprep(const float* __restrict__ vpix, const int* __restrict__ vi,
                           float* __restrict__ rec, unsigned* __restrict__ minmax,
                           int B, int V, int F) {
  int i = blockIdx.x * blockDim.x + threadIdx.x;
  if (i >= B * F) return;
  int b = i / F, f = i - b * F;
  int i0 = vi[f * 3 + 0], i1 = vi[f * 3 + 1], i2 = vi[f * 3 + 2];
  const float* base = vpix + (size_t)b * V * 3;
  float ax = base[(size_t)i0 * 3], ay = base[(size_t)i0 * 3 + 1], az = base[(size_t)i0 * 3 + 2];
  float bx = base[(size_t)i1 * 3], by = base[(size_t)i1 * 3 + 1], bz = base[(size_t)i1 * 3 + 2];
  float cx = base[(size_t)i2 * 3], cy = base[(size_t)i2 * 3 + 1], cz = base[(size_t)i2 * 3 + 2];
  float e0x = __fsub_rn(cx, bx), e0y = __fsub_rn(cy, by);
  float e1x = __fsub_rn(ax, cx), e1y = __fsub_rn(ay, cy);
  float e2x = __fsub_rn(bx, ax), e2y = __fsub_rn(by, ay);
  float area = __fsub_rn(__fmul_rn(e2x, __fsub_rn(cy, ay)), __fmul_rn(e2y, __fsub_rn(cx, ax)));
  float s = (area > 0.f) ? 1.f : ((area < 0.f) ? -1.f : 0.f);
  bool nz = fabsf(area) > 1e-8f;
  bool zv = (az > 0.f) && (bz > 0.f) && (cz > 0.f);
  float sprime = (nz && zv) ? s : __uint_as_float(0x7fc00000u);  // NaN fails all >=0 tests
  float ar = nz ? area : 1.0f;
  float zmin = fminf(az, fminf(bz, cz));
  float* r = rec + (size_t)i * REC_STRIDE;
  r[0] = ax; r[1] = ay; r[2] = bx; r[3] = by; r[4] = cx; r[5] = cy;
  r[6] = e0x; r[7] = e0y; r[8] = e1x; r[9] = e1y; r[10] = e2x; r[11] = e2y;
  r[12] = az; r[13] = bz; r[14] = cz; r[15] = sprime; r[16] = ar;
  r[17] = fminf(ax, fminf(bx, cx));
  r[18] = fmaxf(ax, fmaxf(bx, cx));
  r[19] = fminf(ay, fminf(by, cy));
  r[20] = fmaxf(ay, fmaxf(by, cy));
  r[21] = zmin; r[22] = 0.f; r[23] = 0.f;
  if (minmax && zmin == zmin) {  // not NaN
    unsigned k = fkey(zmin);
    atomicMin(&minmax[0], k);
    atomicMax(&minmax[1], k);
  }
}

// ---------------- counting sort by zmin ----------------
__global__ void k_hist(const float* __restrict__ rec, const unsigned* __restrict__ minmax,
                       int* __restrict__ hist, int B, int F) {
  int i = blockIdx.x * blockDim.x + threadIdx.x;
  if (i >= B * F) return;
  int b = i / F;
  float zmin = rec[(size_t)i * REC_STRIDE + 21];
  float zlo = unfkey(minmax[0]), zhi = unfkey(minmax[1]);
  float scale = (float)NB / fmaxf(zhi - zlo, 1e-12f);
  int bkt = 0;
  if (zmin == zmin) bkt = min(NB - 1, max(0, (int)((zmin - zlo) * scale)));
  atomicAdd(&hist[b * NB + bkt], 1);
}

__global__ void k_scan(const int* __restrict__ hist, int* __restrict__ boff, int B) {
  __shared__ int sh[NB];
  int t = threadIdx.x;
  for (int b = 0; b < B; ++b) {
    sh[t] = hist[b * NB + t];
    __syncthreads();
    int self = sh[t];
    for (int ofs = 1; ofs < NB; ofs <<= 1) {
      int u = (t >= ofs) ? sh[t - ofs] : 0;
      __syncthreads();
      sh[t] += u;
      __syncthreads();
    }
    boff[b * NB + t] = sh[t] - self;  // exclusive
    __syncthreads();
  }
}

__global__ void k_scatter(const float* __restrict__ rec, const unsigned* __restrict__ minmax,
                          const int* __restrict__ boff, int* __restrict__ cursor,
                          int* __restrict__ order, float* __restrict__ zfloor,
                          int B, int F) {
  int i = blockIdx.x * blockDim.x + threadIdx.x;
  if (i >= B * F) return;
  int b = i / F, f = i - b * F;
  float zmin = rec[(size_t)i * REC_STRIDE + 21];
  float zlo = unfkey(minmax[0]), zhi = unfkey(minmax[1]);
  float rng = fmaxf(zhi - zlo, 1e-12f);
  float scale = (float)NB / rng;
  int bkt = 0;
  if (zmin == zmin) bkt = min(NB - 1, max(0, (int)((zmin - zlo) * scale)));
  float floorval = zlo + (float)bkt * (rng / (float)NB);
  int pos = boff[b * NB + bkt] + atomicAdd(&cursor[b * NB + bkt], 1);
  order[(size_t)b * F + pos] = f;
  zfloor[(size_t)b * F + pos] = floorval;
}

// ---------------- sorted rasterizer with early break ----------------
__global__ __launch_bounds__(256) void k_raster_sorted(const float* __restrict__ rec,
                                                       const int* __restrict__ order,
                                                       const float* __restrict__ zfloor,
                                                       unsigned long long* __restrict__ keys,
                                                       int B, int F) {
  int x = threadIdx.x;
  int y = blockIdx.x;
  int b = blockIdx.y;
  int off = blockIdx.z;
  float px = x + 0.5f, py = y + 0.5f;
  float wx0 = (float)(x & ~63) + 0.5f, wx1 = wx0 + 63.0f;  // wave's x-range
  size_t pix = (size_t)b * (H_ * W_) + (size_t)y * W_ + x;
  unsigned long long bestkey = 0x7f800000FFFFFFFFull;
  const float* rb = rec + (size_t)b * F * REC_STRIDE;
  const int* ob = order + (size_t)b * F;
  const float* zfb = zfloor + (size_t)b * F;
  int it = 0;
  for (int pos = off; pos < F; pos += ILV, ++it) {
    float zfl = zfb[pos];  // bucket floor: lower bound on zmin for this & all later faces
    float floor0 = __fmul_rn(zfl, 0.9999f) - 1e-5f;  // safety margin
    float bestz = __uint_as_float((unsigned)(bestkey >> 32));
    if (__all(floor0 > bestz)) break;  // no later face can beat or tie any lane
    if ((it & 15) == 15) {  // periodic cross-wave bestz exchange (atomic: no torn read)
      unsigned long long old = atomicMin(&keys[pix], bestkey);
      if (old < bestkey) bestkey = old;
      bestz = __uint_as_float((unsigned)(bestkey >> 32));
    }
    int f = __builtin_amdgcn_readfirstlane(ob[pos]);
    const float* r = rb + (size_t)f * REC_STRIDE;
    float minx = r[17], maxx = r[18], miny = r[19], maxy = r[20];
    if (py < miny || py > maxy) continue;      // block-uniform row cull
    if (maxx < wx0 || minx > wx1) continue;    // wave-uniform column cull
    float ax = r[0], ay = r[1], bx = r[2], by = r[3], cx = r[4], cy = r[5];
    float e0x = r[6], e0y = r[7], e1x = r[8], e1y = r[9], e2x = r[10], e2y = r[11];
    float sp = r[15];
    float w0 = __fsub_rn(__fmul_rn(e0x, __fsub_rn(py, by)), __fmul_rn(e0y, __fsub_rn(px, bx)));
    float w1 = __fsub_rn(__fmul_rn(e1x, __fsub_rn(py, cy)), __fmul_rn(e1y, __fsub_rn(px, cx)));
    float w2 = __fsub_rn(__fmul_rn(e2x, __fsub_rn(py, ay)), __fmul_rn(e2y, __fsub_rn(px, ax)));
    bool inside = (__fmul_rn(w0, sp) >= 0.f) && (__fmul_rn(w1, sp) >= 0.f) && (__fmul_rn(w2, sp) >= 0.f);
    if (inside) {
      float zmn = r[21];
      // skip divides unless this face could strictly beat/tie bestz
      if (!(__fmul_rn(zmn, 0.9999f) > bestz)) {
        float za = r[12], zb = r[13], zc = r[14], ar = r[16];
        float t0 = __fdiv_rn(__fdiv_rn(w0, ar), za);
        float t1 = __fdiv_rn(__fdiv_rn(w1, ar), zb);
        float t2 = __fdiv_rn(__fdiv_rn(w2, ar), zc);
        float invz = __fadd_rn(__fadd_rn(t0, t1), t2);
        if (invz > 0.f) {
          float z = __fdiv_rn(1.0f, fmaxf(invz, 1e-12f));
          unsigned long long ck = ((unsigned long long)__float_as_uint(z) << 32) | (unsigned)f;
          if (ck < bestkey) { bestkey = ck; atomicMin(&keys[pix], ck); }
        }
      }
    }
  }
  atomicMin(&keys[pix], bestkey);
}

// ---------------- fallback rasterizer (R1, unsorted) ----------------
__global__ __launch_bounds__(256) void k_raster(const float* __restrict__ rec,
                                                unsigned long long* __restrict__ keys,
                                                int B, int F) {
  int x = threadIdx.x;
  int y = blockIdx.x;
  int b = blockIdx.y;
  int seg = blockIdx.z;
  int f0 = (int)((long long)seg * F / SEG);
  int f1 = (int)((long long)(seg + 1) * F / SEG);
  float px = x + 0.5f, py = y + 0.5f;
  float bestz = INFINITY; int besti = -1;
  const float* rb = rec + (size_t)b * F * REC_STRIDE;
  for (int f = f0; f < f1; ++f) {
    const float* r = rb + (size_t)f * REC_STRIDE;
    float miny = r[19], maxy = r[20], minx = r[17], maxx = r[18];
    if (py < miny || py > maxy || maxx < 0.5f || minx > (float)W_ - 0.5f) continue;
    float ax = r[0], ay = r[1], bx = r[2], by = r[3], cx = r[4], cy = r[5];
    float e0x = r[6], e0y = r[7], e1x = r[8], e1y = r[9], e2x = r[10], e2y = r[11];
    float za = r[12], zb = r[13], zc = r[14], sp = r[15], ar = r[16];
    float w0 = __fsub_rn(__fmul_rn(e0x, __fsub_rn(py, by)), __fmul_rn(e0y, __fsub_rn(px, bx)));
    float w1 = __fsub_rn(__fmul_rn(e1x, __fsub_rn(py, cy)), __fmul_rn(e1y, __fsub_rn(px, cx)));
    float w2 = __fsub_rn(__fmul_rn(e2x, __fsub_rn(py, ay)), __fmul_rn(e2y, __fsub_rn(px, ax)));
    bool inside = (__fmul_rn(w0, sp) >= 0.f) && (__fmul_rn(w1, sp) >= 0.f) && (__fmul_rn(w2, sp) >= 0.f);
    if (inside) {
      float t0 = __fdiv_rn(__fdiv_rn(w0, ar), za);
      float t1 = __fdiv_rn(__fdiv_rn(w1, ar), zb);
      float t2 = __fdiv_rn(__fdiv_rn(w2, ar), zc);
      float invz = __fadd_rn(__fadd_rn(t0, t1), t2);
      if (invz > 0.f) {
        float z = __fdiv_rn(1.0f, fmaxf(invz, 1e-12f));
        if (z < bestz) { bestz = z; besti = f; }
      }
    }
  }
  if (besti >= 0) {
    unsigned long long key = ((unsigned long long)__float_as_uint(bestz) << 32) | (unsigned)besti;
    atomicMin(&keys[(size_t)b * (H_ * W_) + y * W_ + x], key);
  }
}

__global__ void k_resolve(const unsigned long long* __restrict__ keys, float* __restrict__ idxout, int n) {
  int i = blockIdx.x * blockDim.x + threadIdx.x;
  if (i >= n) return;
  unsigned long long k = keys[i];
  unsigned zb = (unsigned)(k >> 32);
  idxout[i] = (zb >= 0x7f800000u) ? -1.0f : (float)(int)(unsigned)(k & 0xffffffffu);
}

// ---------------- last-resort rasterizer (no workspace) ----------------
__global__ void k_raster_direct(const float* __restrict__ vpix, const int* __restrict__ vi,
                                float* __restrict__ idxout, int B, int V, int F) {
  int p = blockIdx.x * blockDim.x + threadIdx.x;
  if (p >= B * H_ * W_) return;
  int b = p / (H_ * W_); int pid = p - b * (H_ * W_);
  float px = (pid & (W_ - 1)) + 0.5f, py = (pid >> 8) + 0.5f;
  const float* base = vpix + (size_t)b * V * 3;
  float bestz = INFINITY; int besti = -1;
  for (int f = 0; f < F; ++f) {
    int i0 = vi[f * 3], i1 = vi[f * 3 + 1], i2 = vi[f * 3 + 2];
    float ax = base[(size_t)i0 * 3], ay = base[(size_t)i0 * 3 + 1], za = base[(size_t)i0 * 3 + 2];
    float bx = base[(size_t)i1 * 3], by = base[(size_t)i1 * 3 + 1], zb = base[(size_t)i1 * 3 + 2];
    float cx = base[(size_t)i2 * 3], cy = base[(size_t)i2 * 3 + 1], zc = base[(size_t)i2 * 3 + 2];
    float e0x = __fsub_rn(cx, bx), e0y = __fsub_rn(cy, by);
    float e1x = __fsub_rn(ax, cx), e1y = __fsub_rn(ay, cy);
    float e2x = __fsub_rn(bx, ax), e2y = __fsub_rn(by, ay);
    float area = __fsub_rn(__fmul_rn(e2x, __fsub_rn(cy, ay)), __fmul_rn(e2y, __fsub_rn(cx, ax)));
    float s = (area > 0.f) ? 1.f : ((area < 0.f) ? -1.f : 0.f);
    bool nz = fabsf(area) > 1e-8f;
    bool zv = (za > 0.f) && (zb > 0.f) && (zc > 0.f);
    float sp = (nz && zv) ? s : __uint_as_float(0x7fc00000u);
    float ar = nz ? area : 1.0f;
    float w0 = __fsub_rn(__fmul_rn(e0x, __fsub_rn(py, by)), __fmul_rn(e0y, __fsub_rn(px, bx)));
    float w1 = __fsub_rn(__fmul_rn(e1x, __fsub_rn(py, cy)), __fmul_rn(e1y, __fsub_rn(px, cx)));
    float w2 = __fsub_rn(__fmul_rn(e2x, __fsub_rn(py, ay)), __fmul_rn(e2y, __fsub_rn(px, ax)));
    bool inside = (__fmul_rn(w0, sp) >= 0.f) && (__fmul_rn(w1, sp) >= 0.f) && (__fmul_rn(w2, sp) >= 0.f);
    if (inside) {
      float invz = __fadd_rn(__fadd_rn(__fdiv_rn(__fdiv_rn(w0, ar), za),
                                       __fdiv_rn(__fdiv_rn(w1, ar), zb)),
                             __fdiv_rn(__fdiv_rn(w2, ar), zc));
      if (invz > 0.f) {
        float z = __fdiv_rn(1.0f, fmaxf(invz, 1e-12f));
        if (z < bestz) { bestz = z; besti = f; }
      }
    }
  }
  idxout[p] = (float)besti;
}

// ---------------- render + interpolate + grid_sample, fused ----------------
__global__ __launch_bounds__(256) void k_render(const float* __restrict__ vpix, const int* __restrict__ vi,
                                                const int* __restrict__ vti, const float* __restrict__ vt,
                                                const float* __restrict__ tex, const float* __restrict__ idxin,
                                                float* __restrict__ o_img, float* __restrict__ o_depth,
                                                float* __restrict__ o_vt, float* __restrict__ o_bary,
                                                float* __restrict__ o_mask,
                                                int B, int V, int F, int TH, int TW) {
  int p = blockIdx.x * blockDim.x + threadIdx.x;
  if (p >= B * H_ * W_) return;
  int HW = H_ * W_;
  int b = p / HW; int pid = p - b * HW;
  int y = pid >> 8, x = pid & (W_ - 1);
  int idx = (int)idxin[p];
  size_t pix2 = (size_t)b * 2 * HW + pid;
  size_t pix3 = (size_t)b * 3 * HW + pid;
  if (idx < 0) {
    o_depth[p] = 0.f; o_mask[p] = 0.f;
    o_vt[pix2] = 0.f; o_vt[pix2 + HW] = 0.f;
    o_bary[pix3] = 0.f; o_bary[pix3 + HW] = 0.f; o_bary[pix3 + 2 * HW] = 0.f;
    o_img[pix3] = 0.f; o_img[pix3 + HW] = 0.f; o_img[pix3 + 2 * HW] = 0.f;
    return;
  }
  const float* base = vpix + (size_t)b * V * 3;
  int i0 = vi[idx * 3], i1 = vi[idx * 3 + 1], i2 = vi[idx * 3 + 2];
  float ax = base[(size_t)i0 * 3], ay = base[(size_t)i0 * 3 + 1], az = base[(size_t)i0 * 3 + 2];
  float bx = base[(size_t)i1 * 3], by = base[(size_t)i1 * 3 + 1], bz = base[(size_t)i1 * 3 + 2];
  float cx = base[(size_t)i2 * 3], cy = base[(size_t)i2 * 3 + 1], cz = base[(size_t)i2 * 3 + 2];
  float ptx = x + 0.5f, pty = y + 0.5f;
  float w0 = __fsub_rn(__fmul_rn(__fsub_rn(cx, bx), __fsub_rn(pty, by)),
                       __fmul_rn(__fsub_rn(cy, by), __fsub_rn(ptx, bx)));
  float w1 = __fsub_rn(__fmul_rn(__fsub_rn(ax, cx), __fsub_rn(pty, cy)),
                       __fmul_rn(__fsub_rn(ay, cy), __fsub_rn(ptx, cx)));
  float w2 = __fsub_rn(__fmul_rn(__fsub_rn(bx, ax), __fsub_rn(pty, ay)),
                       __fmul_rn(__fsub_rn(by, ay), __fsub_rn(ptx, ax)));
  float area = __fadd_rn(__fadd_rn(w0, w1), w2);
  float ar = (fabsf(area) > 1e-8f) ? area : 1.0f;
  float f0 = __fdiv_rn(__fdiv_rn(w0, ar), fmaxf(az, 1e-8f));
  float f1 = __fdiv_rn(__fdiv_rn(w1, ar), fmaxf(bz, 1e-8f));
  float f2 = __fdiv_rn(__fdiv_rn(w2, ar), fmaxf(cz, 1e-8f));
  float invz = __fadd_rn(__fadd_rn(f0, f1), f2);
  float invz_s = (fabsf(invz) > 1e-12f) ? invz : 1.0f;
  float depth = __fdiv_rn(1.0f, invz_s);
  float bary0 = __fdiv_rn(f0, invz_s);
  float bary1 = __fdiv_rn(f1, invz_s);
  float bary2 = __fdiv_rn(f2, invz_s);
  o_depth[p] = depth; o_mask[p] = 1.0f;
  o_bary[pix3] = bary0; o_bary[pix3 + HW] = bary1; o_bary[pix3 + 2 * HW] = bary2;
  int t0 = vti[idx * 3], t1 = vti[idx * 3 + 1], t2 = vti[idx * 3 + 2];
  float u0x = __fsub_rn(__fmul_rn(vt[(size_t)t0 * 2], 2.f), 1.f);
  float u0y = __fsub_rn(__fmul_rn(vt[(size_t)t0 * 2 + 1], 2.f), 1.f);
  float u1x = __fsub_rn(__fmul_rn(vt[(size_t)t1 * 2], 2.f), 1.f);
  float u1y = __fsub_rn(__fmul_rn(vt[(size_t)t1 * 2 + 1], 2.f), 1.f);
  float u2x = __fsub_rn(__fmul_rn(vt[(size_t)t2 * 2], 2.f), 1.f);
  float u2y = __fsub_rn(__fmul_rn(vt[(size_t)t2 * 2 + 1], 2.f), 1.f);
  float gx = __fadd_rn(__fadd_rn(__fmul_rn(u0x, bary0), __fmul_rn(u1x, bary1)), __fmul_rn(u2x, bary2));
  float gy = __fadd_rn(__fadd_rn(__fmul_rn(u0y, bary0), __fmul_rn(u1y, bary1)), __fmul_rn(u2y, bary2));
  o_vt[pix2] = gx; o_vt[pix2 + HW] = gy;
  float sx = __fsub_rn(__fdiv_rn(__fmul_rn(__fadd_rn(gx, 1.0f), (float)TW), 2.0f), 0.5f);
  float sy = __fsub_rn(__fdiv_rn(__fmul_rn(__fadd_rn(gy, 1.0f), (float)TH), 2.0f), 0.5f);
  float x0f = floorf(sx), y0f = floorf(sy);
  float wx = __fsub_rn(sx, x0f), wy = __fsub_rn(sy, y0f);
  float omx = __fsub_rn(1.0f, wx), omy = __fsub_rn(1.0f, wy);
  int x0 = (int)x0f, y0 = (int)y0f;
  int x1 = x0 + 1, y1 = y0 + 1;
  bool v00 = (x0 >= 0) && (x0 < TW) && (y0 >= 0) && (y0 < TH);
  bool v10 = (x1 >= 0) && (x1 < TW) && (y0 >= 0) && (y0 < TH);
  bool v01 = (x0 >= 0) && (x0 < TW) && (y1 >= 0) && (y1 < TH);
  bool v11 = (x1 >= 0) && (x1 < TW) && (y1 >= 0) && (y1 < TH);
  int x0c = min(max(x0, 0), TW - 1), x1c = min(max(x1, 0), TW - 1);
  int y0c = min(max(y0, 0), TH - 1), y1c = min(max(y1, 0), TH - 1);
  const float* tb = tex + (size_t)b * 3 * TH * TW;
  #pragma unroll
  for (int ch = 0; ch < 3; ++ch) {
    const float* tc = tb + (size_t)ch * TH * TW;
    float g00 = v00 ? tc[(size_t)y0c * TW + x0c] : 0.f;
    float g10 = v10 ? tc[(size_t)y0c * TW + x1c] : 0.f;
    float g01 = v01 ? tc[(size_t)y1c * TW + x0c] : 0.f;
    float g11 = v11 ? tc[(size_t)y1c * TW + x1c] : 0.f;
    float r = __fmul_rn(__fmul_rn(g00, omx), omy);
    r = __fadd_rn(r, __fmul_rn(__fmul_rn(g10, wx), omy));
    r = __fadd_rn(r, __fmul_rn(__fmul_rn(g01, omx), wy));
    r = __fadd_rn(r, __fmul_rn(__fmul_rn(g11, wx), wy));
    o_img[pix3 + (size_t)ch * HW] = r;
  }
}

extern "C" void kernel_launch(void* const* d_in, const int* in_sizes, int n_in,
                              void* d_out, int out_size, void* d_ws, size_t ws_size,
                              hipStream_t stream) {
  const float* verts = (const float*)d_in[0];
  const float* tex   = (const float*)d_in[1];
  const float* Km    = (const float*)d_in[2];
  const float* Rt    = (const float*)d_in[3];
  const float* vt    = (const float*)d_in[4];
  const int*   vi    = (const int*)d_in[5];
  const int*   vti   = (const int*)d_in[6];

  int B = in_sizes[2] / 9;
  int V = in_sizes[0] / (3 * B);
  int F = in_sizes[5] / 3;
  long texhw = (long)in_sizes[1] / (B * 3);
  int TH = (int)(sqrt((double)texhw) + 0.5);
  int TW = TH;
  const int HW = H_ * W_;

  float* out = (float*)d_out;
  float* o_img   = out;
  float* o_depth = o_img + (size_t)B * 3 * HW;
  float* o_vpix  = o_depth + (size_t)B * HW;
  float* o_vt    = o_vpix + (size_t)B * V * 3;
  float* o_idx   = o_vt + (size_t)B * 2 * HW;
  float* o_bary  = o_idx + (size_t)B * HW;
  float* o_mask  = o_bary + (size_t)B * 3 * HW;

  k_transform<<<(B * V + 255) / 256, 256, 0, stream>>>(verts, Km, Rt, o_vpix, B, V);

  size_t keysBytes   = (size_t)B * HW * 8;
  size_t recBytes    = (size_t)B * F * REC_STRIDE * 4;
  size_t orderBytes  = (size_t)B * F * 4;
  size_t zfloorBytes = (size_t)B * F * 4;
  size_t histBytes   = (size_t)B * NB * 4;
  size_t needSorted = keysBytes + recBytes + orderBytes + zfloorBytes + 3 * histBytes + 16;
  size_t needBasic  = keysBytes + recBytes;

  if (ws_size >= needSorted) {
    char* w = (char*)d_ws;
    unsigned long long* keys = (unsigned long long*)w;            w += keysBytes;
    float* rec    = (float*)w;                                    w += recBytes;
    int*   order  = (int*)w;                                      w += orderBytes;
    float* zfl    = (float*)w;                                    w += zfloorBytes;
    int*   hist   = (int*)w;                                      w += histBytes;
    int*   boff   = (int*)w;                                      w += histBytes;
    int*   cursor = (int*)w;                                      w += histBytes;
    unsigned* minmax = (unsigned*)w;

    k_init<<<(B * HW + 255) / 256, 256, 0, stream>>>(keys, B * HW, hist, cursor, B * NB, minmax);
    k_faceprep<<<(B * F + 255) / 256, 256, 0, stream>>>(o_vpix, vi, rec, minmax, B, V, F);
    k_hist<<<(B * F + 255) / 256, 256, 0, stream>>>(rec, minmax, hist, B, F);
    k_scan<<<1, NB, 0, stream>>>(hist, boff, B);
    k_scatter<<<(B * F + 255) / 256, 256, 0, stream>>>(rec, minmax, boff, cursor, order, zfl, B, F);
    dim3 rg(H_, B, ILV);
    k_raster_sorted<<<rg, 256, 0, stream>>>(rec, order, zfl, keys, B, F);
    k_resolve<<<(B * HW + 255) / 256, 256, 0, stream>>>(keys, o_idx, B * HW);
  } else if (ws_size >= needBasic) {
    unsigned long long* keys = (unsigned long long*)d_ws;
    float* rec = (float*)((char*)d_ws + keysBytes);
    k_init<<<(B * HW + 255) / 256, 256, 0, stream>>>(keys, B * HW, (int*)nullptr, (int*)nullptr, 0, (unsigned*)nullptr);
    k_faceprep<<<(B * F + 255) / 256, 256, 0, stream>>>(o_vpix, vi, rec, (unsigned*)nullptr, B, V, F);
    dim3 rg(H_, B, SEG);
    k_raster<<<rg, 256, 0, stream>>>(rec, keys, B, F);
    k_resolve<<<(B * HW + 255) / 256, 256, 0, stream>>>(keys, o_idx, B * HW);
  } else {
    k_raster_direct<<<(B * HW + 255) / 256, 256, 0, stream>>>(o_vpix, vi, o_idx, B, V, F);
  }

  k_render<<<(B * HW + 255) / 256, 256, 0, stream>>>(o_vpix, vi, vti, vt, tex, o_idx,
                                                     o_img, o_depth, o_vt, o_bary, o_mask,
                                                     B, V, F, TH, TW);
}

// Round 3
// 405.850 us; speedup vs baseline: 4.4243x; 1.2691x over previous
//
#include <hip/hip_runtime.h>
#include <cmath>

#define H_ 256
#define W_ 256
#define SEG 4
#define NB 256          // sort buckets
#define REC_STRIDE 24   // floats per face record (unsorted staging)
#define INITKEY 0x7f800000FFFFFFFFull

__device__ inline unsigned fkey(float f) {
  unsigned u = __float_as_uint(f);
  return (u & 0x80000000u) ? ~u : (u | 0x80000000u);
}
__device__ inline float unfkey(unsigned k) {
  return (k & 0x80000000u) ? __uint_as_float(k & 0x7fffffffu) : __uint_as_float(~k);
}

// ---------------- transform: v_pix = [Kx/z, Ky/z, z] ----------------
__global__ void k_transform(const float* __restrict__ verts, const float* __restrict__ Km,
                            const float* __restrict__ Rt, float* __restrict__ vpix,
                            int B, int V) {
  int i = blockIdx.x * blockDim.x + threadIdx.x;
  if (i >= B * V) return;
  int b = i / V;
  float x = verts[(size_t)i * 3 + 0], y = verts[(size_t)i * 3 + 1], z = verts[(size_t)i * 3 + 2];
  const float* R = Rt + (size_t)b * 12;
  float cx = __fadd_rn(__fadd_rn(__fadd_rn(__fmul_rn(R[0], x), __fmul_rn(R[1], y)), __fmul_rn(R[2], z)), R[3]);
  float cy = __fadd_rn(__fadd_rn(__fadd_rn(__fmul_rn(R[4], x), __fmul_rn(R[5], y)), __fmul_rn(R[6], z)), R[7]);
  float cz = __fadd_rn(__fadd_rn(__fadd_rn(__fmul_rn(R[8], x), __fmul_rn(R[9], y)), __fmul_rn(R[10], z)), R[11]);
  const float* Kb = Km + (size_t)b * 9;
  float px = __fadd_rn(__fadd_rn(__fmul_rn(Kb[0], cx), __fmul_rn(Kb[1], cy)), __fmul_rn(Kb[2], cz));
  float py = __fadd_rn(__fadd_rn(__fmul_rn(Kb[3], cx), __fmul_rn(Kb[4], cy)), __fmul_rn(Kb[5], cz));
  vpix[(size_t)i * 3 + 0] = __fdiv_rn(px, cz);
  vpix[(size_t)i * 3 + 1] = __fdiv_rn(py, cz);
  vpix[(size_t)i * 3 + 2] = cz;
}

// ---------------- init workspace ----------------
__global__ void k_init(unsigned long long* __restrict__ keys, int nkeys,
                       int* __restrict__ hist, int* __restrict__ cursor, int nbkt,
                       unsigned* __restrict__ minmax) {
  int i = blockIdx.x * blockDim.x + threadIdx.x;
  if (keys && i < nkeys) keys[i] = INITKEY;  // (inf, -1)
  if (i < nbkt) { hist[i] = 0; cursor[i] = 0; }
  if (i == 0 && minmax) { minmax[0] = 0xFFFFFFFFu; minmax[1] = 0u; }
}

// ---------------- per-face precompute (unsorted staging) ----------------
// rec: ax,ay,bx,by,cx,cy, e0x,e0y,e1x,e1y,e2x,e2y, za,zb,zc, sprime, ar,
//      minx,maxx,miny,maxy, zmin, pad*2
__global__ void k_faceprep(const float* __restrict__ vpix, const int* __restrict__ vi,
                           float* __restrict__ rec, unsigned* __restrict__ minmax,
                           int B, int V, int F) {
  int i = blockIdx.x * blockDim.x + threadIdx.x;
  if (i >= B * F) return;
  int b = i / F, f = i - b * F;
  int i0 = vi[f * 3 + 0], i1 = vi[f * 3 + 1], i2 = vi[f * 3 + 2];
  const float* base = vpix + (size_t)b * V * 3;
  float ax = base[(size_t)i0 * 3], ay = base[(size_t)i0 * 3 + 1], az = base[(size_t)i0 * 3 + 2];
  float bx = base[(size_t)i1 * 3], by = base[(size_t)i1 * 3 + 1], bz = base[(size_t)i1 * 3 + 2];
  float cx = base[(size_t)i2 * 3], cy = base[(size_t)i2 * 3 + 1], cz = base[(size_t)i2 * 3 + 2];
  float e0x = __fsub_rn(cx, bx), e0y = __fsub_rn(cy, by);
  float e1x = __fsub_rn(ax, cx), e1y = __fsub_rn(ay, cy);
  float e2x = __fsub_rn(bx, ax), e2y = __fsub_rn(by, ay);
  float area = __fsub_rn(__fmul_rn(e2x, __fsub_rn(cy, ay)), __fmul_rn(e2y, __fsub_rn(cx, ax)));
  float s = (area > 0.f) ? 1.f : ((area < 0.f) ? -1.f : 0.f);
  bool nz = fabsf(area) > 1e-8f;
  bool zv = (az > 0.f) && (bz > 0.f) && (cz > 0.f);
  float sprime = (nz && zv) ? s : __uint_as_float(0x7fc00000u);  // NaN fails all >=0 tests
  float ar = nz ? area : 1.0f;
  float zmin = fminf(az, fminf(bz, cz));
  float* r = rec + (size_t)i * REC_STRIDE;
  r[0] = ax; r[1] = ay; r[2] = bx; r[3] = by; r[4] = cx; r[5] = cy;
  r[6] = e0x; r[7] = e0y; r[8] = e1x; r[9] = e1y; r[10] = e2x; r[11] = e2y;
  r[12] = az; r[13] = bz; r[14] = cz; r[15] = sprime; r[16] = ar;
  r[17] = fminf(ax, fminf(bx, cx));
  r[18] = fmaxf(ax, fmaxf(bx, cx));
  r[19] = fminf(ay, fminf(by, cy));
  r[20] = fmaxf(ay, fmaxf(by, cy));
  r[21] = zmin; r[22] = 0.f; r[23] = 0.f;
  if (minmax && zmin == zmin) {  // not NaN
    unsigned k = fkey(zmin);
    atomicMin(&minmax[0], k);
    atomicMax(&minmax[1], k);
  }
}

// ---------------- counting sort by zmin ----------------
__global__ void k_hist(const float* __restrict__ rec, const unsigned* __restrict__ minmax,
                       int* __restrict__ hist, int B, int F) {
  int i = blockIdx.x * blockDim.x + threadIdx.x;
  if (i >= B * F) return;
  int b = i / F;
  float zmin = rec[(size_t)i * REC_STRIDE + 21];
  float zlo = unfkey(minmax[0]), zhi = unfkey(minmax[1]);
  float scale = (float)NB / fmaxf(zhi - zlo, 1e-12f);
  int bkt = 0;
  if (zmin == zmin) bkt = min(NB - 1, max(0, (int)((zmin - zlo) * scale)));
  atomicAdd(&hist[b * NB + bkt], 1);
}

__global__ void k_scan(const int* __restrict__ hist, int* __restrict__ boff, int B) {
  __shared__ int sh[NB];
  int t = threadIdx.x;
  for (int b = 0; b < B; ++b) {
    sh[t] = hist[b * NB + t];
    __syncthreads();
    int self = sh[t];
    for (int ofs = 1; ofs < NB; ofs <<= 1) {
      int u = (t >= ofs) ? sh[t - ofs] : 0;
      __syncthreads();
      sh[t] += u;
      __syncthreads();
    }
    boff[b * NB + t] = sh[t] - self;  // exclusive
    __syncthreads();
  }
}

// scatter into zmin-sorted SoA: srec (5xfloat4), sbb (bbox float4), szf (bucket floor)
__global__ void k_scatter(const float* __restrict__ rec, const unsigned* __restrict__ minmax,
                          const int* __restrict__ boff, int* __restrict__ cursor,
                          float4* __restrict__ srec, float4* __restrict__ sbb,
                          float* __restrict__ szf, int B, int F) {
  int i = blockIdx.x * blockDim.x + threadIdx.x;
  if (i >= B * F) return;
  int b = i / F, f = i - b * F;
  const float* r = rec + (size_t)i * REC_STRIDE;
  float zmin = r[21];
  float zlo = unfkey(minmax[0]), zhi = unfkey(minmax[1]);
  float rng = fmaxf(zhi - zlo, 1e-12f);
  float scale = (float)NB / rng;
  int bkt = 0;
  if (zmin == zmin) bkt = min(NB - 1, max(0, (int)((zmin - zlo) * scale)));
  float floorval = zlo + (float)bkt * (rng / (float)NB);
  int pos = boff[b * NB + bkt] + atomicAdd(&cursor[b * NB + bkt], 1);
  size_t gp = (size_t)b * F + pos;
  szf[gp] = floorval;
  sbb[gp] = make_float4(r[17], r[18], r[19], r[20]);  // minx,maxx,miny,maxy
  float4* d = srec + gp * 5;
  d[0] = make_float4(r[0], r[1], r[2], r[3]);    // ax,ay,bx,by
  d[1] = make_float4(r[4], r[5], r[6], r[7]);    // cx,cy,e0x,e0y
  d[2] = make_float4(r[8], r[9], r[10], r[11]);  // e1x,e1y,e2x,e2y
  d[3] = make_float4(r[12], r[13], r[14], r[15]);// za,zb,zc,sp
  d[4] = make_float4(r[16], r[21], __int_as_float(f), 0.f);  // ar,zmin,fid
}

// ---------------- tile rasterizer: 64 pixels/block, 4 face-subset waves, LDS exchange ----
__global__ __launch_bounds__(256) void k_raster_tile(const float4* __restrict__ srec,
                                                     const float4* __restrict__ sbb,
                                                     const float* __restrict__ szf,
                                                     float* __restrict__ o_idx,
                                                     int B, int F) {
  int seg = blockIdx.x;            // x-segment of 64 pixels
  int y   = blockIdx.y;
  int b   = blockIdx.z;
  int tid = threadIdx.x;
  int w = tid >> 6, lane = tid & 63;
  __shared__ unsigned long long sk[64];
  if (tid < 64) sk[tid] = INITKEY;
  __syncthreads();
  const float4* srb  = srec + (size_t)b * F * 5;
  const float4* sbbb = sbb + (size_t)b * F;
  const float*  szfb = szf + (size_t)b * F;
  float px = seg * 64 + lane + 0.5f, py = y + 0.5f;
  float wx0 = seg * 64 + 0.5f, wx1 = wx0 + 63.0f;
  unsigned long long bestkey = INITKEY;
  float bestz = INFINITY;
  int it = 0;
  int pos = w;
  float zfl = (pos < F) ? szfb[pos] : 0.f;
  float4 bb = (pos < F) ? sbbb[pos] : make_float4(0.f, 0.f, 0.f, 0.f);
  for (; pos < F; pos += 4, ++it) {
    // prefetch next iteration's cull data before the branchy body
    int nxt = pos + 4;
    float zfl_n = 0.f;
    float4 bb_n = bb;
    if (nxt < F) { zfl_n = szfb[nxt]; bb_n = sbbb[nxt]; }
    // early break: no face at pos or later can strictly beat any lane's bestz
    float floor0 = __fmul_rn(zfl, 0.9999f) - 1e-5f;  // safety margin: never skips a tie
    if (__all(floor0 > bestz)) break;
    if ((it & 7) == 7) {  // periodic cross-wave exchange via LDS
      unsigned long long old = atomicMin(&sk[lane], bestkey);
      if (old < bestkey) { bestkey = old; bestz = __uint_as_float((unsigned)(bestkey >> 32)); }
    }
    bool cull = (py < bb.z) || (py > bb.w) || (bb.y < wx0) || (bb.x > wx1);
    if (!cull) {
      float4 r0 = srb[(size_t)pos * 5 + 0];
      float4 r1 = srb[(size_t)pos * 5 + 1];
      float4 r2 = srb[(size_t)pos * 5 + 2];
      float4 r3 = srb[(size_t)pos * 5 + 3];
      float4 r4 = srb[(size_t)pos * 5 + 4];
      float w0 = __fsub_rn(__fmul_rn(r1.z, __fsub_rn(py, r0.w)), __fmul_rn(r1.w, __fsub_rn(px, r0.z)));
      float w1 = __fsub_rn(__fmul_rn(r2.x, __fsub_rn(py, r1.y)), __fmul_rn(r2.y, __fsub_rn(px, r1.x)));
      float w2 = __fsub_rn(__fmul_rn(r2.z, __fsub_rn(py, r0.y)), __fmul_rn(r2.w, __fsub_rn(px, r0.x)));
      float sp = r3.w;
      bool inside = (__fmul_rn(w0, sp) >= 0.f) && (__fmul_rn(w1, sp) >= 0.f) && (__fmul_rn(w2, sp) >= 0.f);
      // divide-skip: only if this face provably can't beat/tie bestz
      if (inside && !(__fmul_rn(r4.y, 0.9999f) > bestz)) {
        float t0 = __fdiv_rn(__fdiv_rn(w0, r4.x), r3.x);
        float t1 = __fdiv_rn(__fdiv_rn(w1, r4.x), r3.y);
        float t2 = __fdiv_rn(__fdiv_rn(w2, r4.x), r3.z);
        float invz = __fadd_rn(__fadd_rn(t0, t1), t2);
        if (invz > 0.f) {
          float z = __fdiv_rn(1.0f, fmaxf(invz, 1e-12f));
          int fid = __float_as_int(r4.z);
          unsigned long long ck = ((unsigned long long)__float_as_uint(z) << 32) | (unsigned)fid;
          if (ck < bestkey) {
            bestkey = ck;
            bestz = __uint_as_float((unsigned)(bestkey >> 32));
            atomicMin(&sk[lane], ck);  // push immediately so other waves see it
          }
        }
      }
    }
    zfl = zfl_n; bb = bb_n;
  }
  atomicMin(&sk[lane], bestkey);
  __syncthreads();
  if (tid < 64) {
    unsigned long long k = sk[tid];
    unsigned zb = (unsigned)(k >> 32);
    o_idx[(size_t)b * (H_ * W_) + (size_t)y * W_ + seg * 64 + tid] =
        (zb >= 0x7f800000u) ? -1.0f : (float)(int)(unsigned)(k & 0xffffffffu);
  }
}

// ---------------- fallback rasterizer (unsorted, global keys) ----------------
__global__ __launch_bounds__(256) void k_raster(const float* __restrict__ rec,
                                                unsigned long long* __restrict__ keys,
                                                int B, int F) {
  int x = threadIdx.x;
  int y = blockIdx.x;
  int b = blockIdx.y;
  int seg = blockIdx.z;
  int f0 = (int)((long long)seg * F / SEG);
  int f1 = (int)((long long)(seg + 1) * F / SEG);
  float px = x + 0.5f, py = y + 0.5f;
  float bestz = INFINITY; int besti = -1;
  const float* rb = rec + (size_t)b * F * REC_STRIDE;
  for (int f = f0; f < f1; ++f) {
    const float* r = rb + (size_t)f * REC_STRIDE;
    float miny = r[19], maxy = r[20], minx = r[17], maxx = r[18];
    if (py < miny || py > maxy || maxx < 0.5f || minx > (float)W_ - 0.5f) continue;
    float e0x = r[6], e0y = r[7], e1x = r[8], e1y = r[9], e2x = r[10], e2y = r[11];
    float za = r[12], zb = r[13], zc = r[14], sp = r[15], ar = r[16];
    float w0 = __fsub_rn(__fmul_rn(e0x, __fsub_rn(py, r[3])), __fmul_rn(e0y, __fsub_rn(px, r[2])));
    float w1 = __fsub_rn(__fmul_rn(e1x, __fsub_rn(py, r[5])), __fmul_rn(e1y, __fsub_rn(px, r[4])));
    float w2 = __fsub_rn(__fmul_rn(e2x, __fsub_rn(py, r[1])), __fmul_rn(e2y, __fsub_rn(px, r[0])));
    bool inside = (__fmul_rn(w0, sp) >= 0.f) && (__fmul_rn(w1, sp) >= 0.f) && (__fmul_rn(w2, sp) >= 0.f);
    if (inside) {
      float t0 = __fdiv_rn(__fdiv_rn(w0, ar), za);
      float t1 = __fdiv_rn(__fdiv_rn(w1, ar), zb);
      float t2 = __fdiv_rn(__fdiv_rn(w2, ar), zc);
      float invz = __fadd_rn(__fadd_rn(t0, t1), t2);
      if (invz > 0.f) {
        float z = __fdiv_rn(1.0f, fmaxf(invz, 1e-12f));
        if (z < bestz) { bestz = z; besti = f; }
      }
    }
  }
  if (besti >= 0) {
    unsigned long long key = ((unsigned long long)__float_as_uint(bestz) << 32) | (unsigned)besti;
    atomicMin(&keys[(size_t)b * (H_ * W_) + y * W_ + x], key);
  }
}

__global__ void k_resolve(const unsigned long long* __restrict__ keys, float* __restrict__ idxout, int n) {
  int i = blockIdx.x * blockDim.x + threadIdx.x;
  if (i >= n) return;
  unsigned long long k = keys[i];
  unsigned zb = (unsigned)(k >> 32);
  idxout[i] = (zb >= 0x7f800000u) ? -1.0f : (float)(int)(unsigned)(k & 0xffffffffu);
}

// ---------------- last-resort rasterizer (no workspace) ----------------
__global__ void k_raster_direct(const float* __restrict__ vpix, const int* __restrict__ vi,
                                float* __restrict__ idxout, int B, int V, int F) {
  int p = blockIdx.x * blockDim.x + threadIdx.x;
  if (p >= B * H_ * W_) return;
  int b = p / (H_ * W_); int pid = p - b * (H_ * W_);
  float px = (pid & (W_ - 1)) + 0.5f, py = (pid >> 8) + 0.5f;
  const float* base = vpix + (size_t)b * V * 3;
  float bestz = INFINITY; int besti = -1;
  for (int f = 0; f < F; ++f) {
    int i0 = vi[f * 3], i1 = vi[f * 3 + 1], i2 = vi[f * 3 + 2];
    float ax = base[(size_t)i0 * 3], ay = base[(size_t)i0 * 3 + 1], za = base[(size_t)i0 * 3 + 2];
    float bx = base[(size_t)i1 * 3], by = base[(size_t)i1 * 3 + 1], zb = base[(size_t)i1 * 3 + 2];
    float cx = base[(size_t)i2 * 3], cy = base[(size_t)i2 * 3 + 1], zc = base[(size_t)i2 * 3 + 2];
    float e0x = __fsub_rn(cx, bx), e0y = __fsub_rn(cy, by);
    float e1x = __fsub_rn(ax, cx), e1y = __fsub_rn(ay, cy);
    float e2x = __fsub_rn(bx, ax), e2y = __fsub_rn(by, ay);
    float area = __fsub_rn(__fmul_rn(e2x, __fsub_rn(cy, ay)), __fmul_rn(e2y, __fsub_rn(cx, ax)));
    float s = (area > 0.f) ? 1.f : ((area < 0.f) ? -1.f : 0.f);
    bool nz = fabsf(area) > 1e-8f;
    bool zv = (za > 0.f) && (zb > 0.f) && (zc > 0.f);
    float sp = (nz && zv) ? s : __uint_as_float(0x7fc00000u);
    float ar = nz ? area : 1.0f;
    float w0 = __fsub_rn(__fmul_rn(e0x, __fsub_rn(py, by)), __fmul_rn(e0y, __fsub_rn(px, bx)));
    float w1 = __fsub_rn(__fmul_rn(e1x, __fsub_rn(py, cy)), __fmul_rn(e1y, __fsub_rn(px, cx)));
    float w2 = __fsub_rn(__fmul_rn(e2x, __fsub_rn(py, ay)), __fmul_rn(e2y, __fsub_rn(px, ax)));
    bool inside = (__fmul_rn(w0, sp) >= 0.f) && (__fmul_rn(w1, sp) >= 0.f) && (__fmul_rn(w2, sp) >= 0.f);
    if (inside) {
      float invz = __fadd_rn(__fadd_rn(__fdiv_rn(__fdiv_rn(w0, ar), za),
                                       __fdiv_rn(__fdiv_rn(w1, ar), zb)),
                             __fdiv_rn(__fdiv_rn(w2, ar), zc));
      if (invz > 0.f) {
        float z = __fdiv_rn(1.0f, fmaxf(invz, 1e-12f));
        if (z < bestz) { bestz = z; besti = f; }
      }
    }
  }
  idxout[p] = (float)besti;
}

// ---------------- render + interpolate + grid_sample, fused ----------------
__global__ __launch_bounds__(256) void k_render(const float* __restrict__ vpix, const int* __restrict__ vi,
                                                const int* __restrict__ vti, const float* __restrict__ vt,
                                                const float* __restrict__ tex, const float* __restrict__ idxin,
                                                float* __restrict__ o_img, float* __restrict__ o_depth,
                                                float* __restrict__ o_vt, float* __restrict__ o_bary,
                                                float* __restrict__ o_mask,
                                                int B, int V, int F, int TH, int TW) {
  int p = blockIdx.x * blockDim.x + threadIdx.x;
  if (p >= B * H_ * W_) return;
  int HW = H_ * W_;
  int b = p / HW; int pid = p - b * HW;
  int y = pid >> 8, x = pid & (W_ - 1);
  int idx = (int)idxin[p];
  size_t pix2 = (size_t)b * 2 * HW + pid;
  size_t pix3 = (size_t)b * 3 * HW + pid;
  if (idx < 0) {
    o_depth[p] = 0.f; o_mask[p] = 0.f;
    o_vt[pix2] = 0.f; o_vt[pix2 + HW] = 0.f;
    o_bary[pix3] = 0.f; o_bary[pix3 + HW] = 0.f; o_bary[pix3 + 2 * HW] = 0.f;
    o_img[pix3] = 0.f; o_img[pix3 + HW] = 0.f; o_img[pix3 + 2 * HW] = 0.f;
    return;
  }
  const float* base = vpix + (size_t)b * V * 3;
  int i0 = vi[idx * 3], i1 = vi[idx * 3 + 1], i2 = vi[idx * 3 + 2];
  float ax = base[(size_t)i0 * 3], ay = base[(size_t)i0 * 3 + 1], az = base[(size_t)i0 * 3 + 2];
  float bx = base[(size_t)i1 * 3], by = base[(size_t)i1 * 3 + 1], bz = base[(size_t)i1 * 3 + 2];
  float cx = base[(size_t)i2 * 3], cy = base[(size_t)i2 * 3 + 1], cz = base[(size_t)i2 * 3 + 2];
  float ptx = x + 0.5f, pty = y + 0.5f;
  float w0 = __fsub_rn(__fmul_rn(__fsub_rn(cx, bx), __fsub_rn(pty, by)),
                       __fmul_rn(__fsub_rn(cy, by), __fsub_rn(ptx, bx)));
  float w1 = __fsub_rn(__fmul_rn(__fsub_rn(ax, cx), __fsub_rn(pty, cy)),
                       __fmul_rn(__fsub_rn(ay, cy), __fsub_rn(ptx, cx)));
  float w2 = __fsub_rn(__fmul_rn(__fsub_rn(bx, ax), __fsub_rn(pty, ay)),
                       __fmul_rn(__fsub_rn(by, ay), __fsub_rn(ptx, ax)));
  float area = __fadd_rn(__fadd_rn(w0, w1), w2);
  float ar = (fabsf(area) > 1e-8f) ? area : 1.0f;
  float f0 = __fdiv_rn(__fdiv_rn(w0, ar), fmaxf(az, 1e-8f));
  float f1 = __fdiv_rn(__fdiv_rn(w1, ar), fmaxf(bz, 1e-8f));
  float f2 = __fdiv_rn(__fdiv_rn(w2, ar), fmaxf(cz, 1e-8f));
  float invz = __fadd_rn(__fadd_rn(f0, f1), f2);
  float invz_s = (fabsf(invz) > 1e-12f) ? invz : 1.0f;
  float depth = __fdiv_rn(1.0f, invz_s);
  float bary0 = __fdiv_rn(f0, invz_s);
  float bary1 = __fdiv_rn(f1, invz_s);
  float bary2 = __fdiv_rn(f2, invz_s);
  o_depth[p] = depth; o_mask[p] = 1.0f;
  o_bary[pix3] = bary0; o_bary[pix3 + HW] = bary1; o_bary[pix3 + 2 * HW] = bary2;
  int t0 = vti[idx * 3], t1 = vti[idx * 3 + 1], t2 = vti[idx * 3 + 2];
  float u0x = __fsub_rn(__fmul_rn(vt[(size_t)t0 * 2], 2.f), 1.f);
  float u0y = __fsub_rn(__fmul_rn(vt[(size_t)t0 * 2 + 1], 2.f), 1.f);
  float u1x = __fsub_rn(__fmul_rn(vt[(size_t)t1 * 2], 2.f), 1.f);
  float u1y = __fsub_rn(__fmul_rn(vt[(size_t)t1 * 2 + 1], 2.f), 1.f);
  float u2x = __fsub_rn(__fmul_rn(vt[(size_t)t2 * 2], 2.f), 1.f);
  float u2y = __fsub_rn(__fmul_rn(vt[(size_t)t2 * 2 + 1], 2.f), 1.f);
  float gx = __fadd_rn(__fadd_rn(__fmul_rn(u0x, bary0), __fmul_rn(u1x, bary1)), __fmul_rn(u2x, bary2));
  float gy = __fadd_rn(__fadd_rn(__fmul_rn(u0y, bary0), __fmul_rn(u1y, bary1)), __fmul_rn(u2y, bary2));
  o_vt[pix2] = gx; o_vt[pix2 + HW] = gy;
  float sx = __fsub_rn(__fdiv_rn(__fmul_rn(__fadd_rn(gx, 1.0f), (float)TW), 2.0f), 0.5f);
  float sy = __fsub_rn(__fdiv_rn(__fmul_rn(__fadd_rn(gy, 1.0f), (float)TH), 2.0f), 0.5f);
  float x0f = floorf(sx), y0f = floorf(sy);
  float wx = __fsub_rn(sx, x0f), wy = __fsub_rn(sy, y0f);
  float omx = __fsub_rn(1.0f, wx), omy = __fsub_rn(1.0f, wy);
  int x0 = (int)x0f, y0 = (int)y0f;
  int x1 = x0 + 1, y1 = y0 + 1;
  bool v00 = (x0 >= 0) && (x0 < TW) && (y0 >= 0) && (y0 < TH);
  bool v10 = (x1 >= 0) && (x1 < TW) && (y0 >= 0) && (y0 < TH);
  bool v01 = (x0 >= 0) && (x0 < TW) && (y1 >= 0) && (y1 < TH);
  bool v11 = (x1 >= 0) && (x1 < TW) && (y1 >= 0) && (y1 < TH);
  int x0c = min(max(x0, 0), TW - 1), x1c = min(max(x1, 0), TW - 1);
  int y0c = min(max(y0, 0), TH - 1), y1c = min(max(y1, 0), TH - 1);
  const float* tb = tex + (size_t)b * 3 * TH * TW;
  #pragma unroll
  for (int ch = 0; ch < 3; ++ch) {
    const float* tc = tb + (size_t)ch * TH * TW;
    float g00 = v00 ? tc[(size_t)y0c * TW + x0c] : 0.f;
    float g10 = v10 ? tc[(size_t)y0c * TW + x1c] : 0.f;
    float g01 = v01 ? tc[(size_t)y1c * TW + x0c] : 0.f;
    float g11 = v11 ? tc[(size_t)y1c * TW + x1c] : 0.f;
    float r = __fmul_rn(__fmul_rn(g00, omx), omy);
    r = __fadd_rn(r, __fmul_rn(__fmul_rn(g10, wx), omy));
    r = __fadd_rn(r, __fmul_rn(__fmul_rn(g01, omx), wy));
    r = __fadd_rn(r, __fmul_rn(__fmul_rn(g11, wx), wy));
    o_img[pix3 + (size_t)ch * HW] = r;
  }
}

extern "C" void kernel_launch(void* const* d_in, const int* in_sizes, int n_in,
                              void* d_out, int out_size, void* d_ws, size_t ws_size,
                              hipStream_t stream) {
  const float* verts = (const float*)d_in[0];
  const float* tex   = (const float*)d_in[1];
  const float* Km    = (const float*)d_in[2];
  const float* Rt    = (const float*)d_in[3];
  const float* vt    = (const float*)d_in[4];
  const int*   vi    = (const int*)d_in[5];
  const int*   vti   = (const int*)d_in[6];

  int B = in_sizes[2] / 9;
  int V = in_sizes[0] / (3 * B);
  int F = in_sizes[5] / 3;
  long texhw = (long)in_sizes[1] / (B * 3);
  int TH = (int)(sqrt((double)texhw) + 0.5);
  int TW = TH;
  const int HW = H_ * W_;

  float* out = (float*)d_out;
  float* o_img   = out;
  float* o_depth = o_img + (size_t)B * 3 * HW;
  float* o_vpix  = o_depth + (size_t)B * HW;
  float* o_vt    = o_vpix + (size_t)B * V * 3;
  float* o_idx   = o_vt + (size_t)B * 2 * HW;
  float* o_bary  = o_idx + (size_t)B * HW;
  float* o_mask  = o_bary + (size_t)B * 3 * HW;

  k_transform<<<(B * V + 255) / 256, 256, 0, stream>>>(verts, Km, Rt, o_vpix, B, V);

  size_t srecBytes   = (size_t)B * F * 5 * 16;   // sorted SoA records
  size_t sbbBytes    = (size_t)B * F * 16;       // sorted bboxes
  size_t recBytes    = (size_t)B * F * REC_STRIDE * 4;
  size_t szfBytes    = (size_t)B * F * 4;
  size_t histBytes   = (size_t)B * NB * 4;
  size_t keysBytes   = (size_t)B * HW * 8;
  size_t needSorted = srecBytes + sbbBytes + recBytes + szfBytes + 3 * histBytes + 16;
  size_t needBasic  = keysBytes + recBytes;

  if (ws_size >= needSorted) {
    char* w = (char*)d_ws;   // 16B-aligned arrays first
    float4* srec = (float4*)w;                                    w += srecBytes;
    float4* sbb  = (float4*)w;                                    w += sbbBytes;
    float*  rec  = (float*)w;                                     w += recBytes;
    float*  szf  = (float*)w;                                     w += szfBytes;
    int*    hist = (int*)w;                                       w += histBytes;
    int*    boff = (int*)w;                                       w += histBytes;
    int*    cursor = (int*)w;                                     w += histBytes;
    unsigned* minmax = (unsigned*)w;

    k_init<<<(B * NB + 255) / 256, 256, 0, stream>>>((unsigned long long*)nullptr, 0, hist, cursor, B * NB, minmax);
    k_faceprep<<<(B * F + 255) / 256, 256, 0, stream>>>(o_vpix, vi, rec, minmax, B, V, F);
    k_hist<<<(B * F + 255) / 256, 256, 0, stream>>>(rec, minmax, hist, B, F);
    k_scan<<<1, NB, 0, stream>>>(hist, boff, B);
    k_scatter<<<(B * F + 255) / 256, 256, 0, stream>>>(rec, minmax, boff, cursor, srec, sbb, szf, B, F);
    dim3 rg(W_ / 64, H_, B);
    k_raster_tile<<<rg, 256, 0, stream>>>(srec, sbb, szf, o_idx, B, F);
  } else if (ws_size >= needBasic) {
    unsigned long long* keys = (unsigned long long*)d_ws;
    float* rec = (float*)((char*)d_ws + keysBytes);
    k_init<<<(B * HW + 255) / 256, 256, 0, stream>>>(keys, B * HW, (int*)nullptr, (int*)nullptr, 0, (unsigned*)nullptr);
    k_faceprep<<<(B * F + 255) / 256, 256, 0, stream>>>(o_vpix, vi, rec, (unsigned*)nullptr, B, V, F);
    dim3 rg(H_, B, SEG);
    k_raster<<<rg, 256, 0, stream>>>(rec, keys, B, F);
    k_resolve<<<(B * HW + 255) / 256, 256, 0, stream>>>(keys, o_idx, B * HW);
  } else {
    k_raster_direct<<<(B * HW + 255) / 256, 256, 0, stream>>>(o_vpix, vi, o_idx, B, V, F);
  }

  k_render<<<(B * HW + 255) / 256, 256, 0, stream>>>(o_vpix, vi, vti, vt, tex, o_idx,
                                                     o_img, o_depth, o_vt, o_bary, o_mask,
                                                     B, V, F, TH, TW);
}